// Round 21
// baseline (543.873 us; speedup 1.0000x reference)
//
#include <hip/hip_runtime.h>
#include <hip/hip_bf16.h>
#include <stdint.h>

#define T_TOK 8192
#define DM 1024
#define DF 4096
#define NE 8
#define NSLOT 136   // max live by-slots: 16384/128 + 8

typedef __attribute__((ext_vector_type(8))) short short8;
typedef __attribute__((ext_vector_type(8))) unsigned short ushort8;
typedef __attribute__((ext_vector_type(4))) float f32x4;

#define AS1 __attribute__((address_space(1)))
#define AS3 __attribute__((address_space(3)))

#define NB_GATE (T_TOK / 4)                    // 2048
#define NB_T1 ((DF / 64) * (DM / 64) * NE)     // 8192
#define NB_T2 ((DM / 64) * (DF / 64) * NE)     // 8192

static __device__ __forceinline__ unsigned short f2bf(float f) {
  union { float f; unsigned int u; } c; c.f = f;
  unsigned int u = c.u;
  unsigned int r = (u + 0x7FFFu + ((u >> 16) & 1u)) >> 16;
  return (unsigned short)r;
}

static __device__ __forceinline__ float gelu_tanh(float v) {
  float y = 0.7978845608028654f * (v + 0.044715f * v * v * v);
  float ay = fabsf(y);
  float e = __expf(-2.0f * ay);
  float th = (1.0f - e) / (1.0f + e);
  th = copysignf(th, y);
  return 0.5f * v * (1.0f + th);
}

__global__ void k_probe(float* out, float v, int n) {
  int i = blockIdx.x * blockDim.x + threadIdx.x;
  for (; i < n; i += gridDim.x * blockDim.x) out[i] = v;
}

// Fused prologue: [0,NB_GATE) gate+out-init; then W1 transpose ONLY.
__global__ void k_prep(const float* __restrict__ x, unsigned short* __restrict__ xb,
                       const float* __restrict__ Wg, const float* __restrict__ bg,
                       const float* __restrict__ W1, unsigned short* __restrict__ w1t,
                       const float* __restrict__ b2, float* __restrict__ out,
                       int* __restrict__ choice2, float* __restrict__ wts) {
  __shared__ float tile[64][65];
  int bid = blockIdx.x;

  if (bid < NB_GATE) {
    int wave = threadIdx.x >> 6, lane = threadIdx.x & 63;
    int t = bid * 4 + wave;
    const float* xr = x + (size_t)t * DM;
    unsigned short* xo = xb + (size_t)t * DM;
    double acc[NE];
#pragma unroll
    for (int e = 0; e < NE; ++e) acc[e] = 0.0;
#pragma unroll
    for (int i = 0; i < 4; ++i) {
      int d = lane * 4 + i * 256;
      float4 v = *(const float4*)(xr + d);
      ushort4 o;
      o.x = f2bf(v.x); o.y = f2bf(v.y); o.z = f2bf(v.z); o.w = f2bf(v.w);
      *(ushort4*)(xo + d) = o;
      float xv[4] = {v.x, v.y, v.z, v.w};
#pragma unroll
      for (int q = 0; q < 4; ++q) {
        const float4* wg = (const float4*)(Wg + (size_t)(d + q) * NE);
        float4 w0 = wg[0], w1 = wg[1];
        acc[0] += (double)xv[q] * w0.x; acc[1] += (double)xv[q] * w0.y;
        acc[2] += (double)xv[q] * w0.z; acc[3] += (double)xv[q] * w0.w;
        acc[4] += (double)xv[q] * w1.x; acc[5] += (double)xv[q] * w1.y;
        acc[6] += (double)xv[q] * w1.z; acc[7] += (double)xv[q] * w1.w;
      }
    }
#pragma unroll
    for (int off = 32; off; off >>= 1)
#pragma unroll
      for (int e = 0; e < NE; ++e) acc[e] += __shfl_xor(acc[e], off);
    int e1i = 0, e2i = 0;
    float w1v = 0.f, w2v = 0.f;
    if (lane == 0) {
      float lg[NE];
#pragma unroll
      for (int e = 0; e < NE; ++e) lg[e] = (float)acc[e] + bg[e];
      float m = lg[0];
#pragma unroll
      for (int e = 1; e < NE; ++e) m = fmaxf(m, lg[e]);
      float s = 0.f, p[NE];
#pragma unroll
      for (int e = 0; e < NE; ++e) { p[e] = expf(lg[e] - m); s += p[e]; }
      float inv = 1.f / s;
      int i1 = 0;
#pragma unroll
      for (int e = 1; e < NE; ++e) if (lg[e] > lg[i1]) i1 = e;
      int i2 = (i1 == 0) ? 1 : 0;
#pragma unroll
      for (int e = 0; e < NE; ++e) if (e != i1 && lg[e] > lg[i2]) i2 = e;
      e1i = i1; e2i = i2;
      w1v = p[i1] * inv; w2v = p[i2] * inv;
      choice2[2 * t] = i1;     wts[2 * t] = w1v;
      choice2[2 * t + 1] = i2; wts[2 * t + 1] = w2v;
    }
    e1i = __shfl(e1i, 0); e2i = __shfl(e2i, 0);
    w1v = __shfl(w1v, 0); w2v = __shfl(w2v, 0);
#pragma unroll
    for (int i = 0; i < 4; ++i) {
      int d = lane * 4 + i * 256;
      float4 a = *(const float4*)(b2 + (size_t)e1i * DM + d);
      float4 b = *(const float4*)(b2 + (size_t)e2i * DM + d);
      float4 o;
      o.x = w1v * a.x + w2v * b.x; o.y = w1v * a.y + w2v * b.y;
      o.z = w1v * a.z + w2v * b.z; o.w = w1v * a.w + w2v * b.w;
      *(float4*)(out + (size_t)t * DM + d) = o;
    }
    return;
  }

  // W1 transpose: [E][DM][DF] fp32 -> [E][DF][DM] bf16
  {
    int b2i = bid - NB_GATE;
    int e = b2i >> 10, rem = b2i & 1023;
    int byy = rem >> 6, bxx = rem & 63;
    int r0 = byy * 64, c0 = bxx * 64;
    const float* src = W1 + (size_t)e * DM * DF;
    unsigned short* dst = w1t + (size_t)e * DM * DF;
    int tx = threadIdx.x & 15, ty = threadIdx.x >> 4;
#pragma unroll
    for (int i = 0; i < 4; ++i) {
      int r = ty + i * 16;
      float4 v = *(const float4*)(src + (size_t)(r0 + r) * DF + c0 + tx * 4);
      tile[r][tx * 4 + 0] = v.x; tile[r][tx * 4 + 1] = v.y;
      tile[r][tx * 4 + 2] = v.z; tile[r][tx * 4 + 3] = v.w;
    }
    __syncthreads();
    int tx2 = threadIdx.x & 7, ty2 = threadIdx.x >> 3;
#pragma unroll
    for (int i = 0; i < 2; ++i) {
      int c = ty2 + i * 32;
      ushort8 o;
#pragma unroll
      for (int j = 0; j < 8; ++j) o[j] = f2bf(tile[tx2 * 8 + j][c]);
      *(ushort8*)(dst + (size_t)(c0 + c) * DM + r0 + tx2 * 8) = o;
    }
  }
}

// Parallel deterministic compaction: 8 blocks (one per expert) x 4 waves.
__global__ void k_bucket(const int* __restrict__ choice2, const float* __restrict__ wts,
                         int* __restrict__ counts, int* __restrict__ offsets,
                         int* __restrict__ btok, float* __restrict__ bw,
                         int* __restrict__ work) {
  __shared__ int qc[4][NE];
  int e = blockIdx.x;
  int tid = threadIdx.x;
  int w = tid >> 6, lane = tid & 63;
  const int QUARTER = 2 * T_TOK / 4;  // 4096
  int base = w * QUARTER;
  unsigned long long below = (lane == 0) ? 0ull : ((1ull << lane) - 1ull);

  int cq[NE];
#pragma unroll
  for (int q = 0; q < NE; ++q) cq[q] = 0;
  for (int i0 = 0; i0 < QUARTER; i0 += 64) {
    int ce = choice2[base + i0 + lane];
#pragma unroll
    for (int q = 0; q < NE; ++q)
      cq[q] += (int)__popcll(__ballot(ce == q));
  }
  if (lane == 0) {
#pragma unroll
    for (int q = 0; q < NE; ++q) qc[w][q] = cq[q];
  }
  __syncthreads();

  int total[NE];
#pragma unroll
  for (int q = 0; q < NE; ++q) total[q] = qc[0][q] + qc[1][q] + qc[2][q] + qc[3][q];
  int pos = 0;
#pragma unroll
  for (int ww = 0; ww < 4; ++ww) if (ww < w) pos += qc[ww][e];

  if (e == 0 && tid == 0) {
    int s = 0;
    for (int q = 0; q < NE; ++q) { counts[q] = total[q]; offsets[q] = s; s += total[q]; }
    int idx = 0;
    for (int q = 0; q < NE; ++q) {
      int nby = (total[q] + 127) >> 7;
      for (int j = 0; j < nby; ++j) work[idx++] = (q << 20) | (j << 7);
    }
    while (idx < NSLOT) work[idx++] = -1;
  }

  for (int i0 = 0; i0 < QUARTER; i0 += 64) {
    int idx = base + i0 + lane;
    int ce = choice2[idx];
    float wt = wts[idx];
    unsigned long long m = __ballot(ce == e);
    if (ce == e) {
      int r = (int)__popcll(m & below);
      btok[e * T_TOK + pos + r] = idx >> 1;
      bw[e * T_TOK + pos + r] = wt;
    }
    pos += (int)__popcll(m);
  }
}

// GEMM1 (BK=64, R17 core) + W2-transpose carrier (R20 win).
__global__ __launch_bounds__(256, 4) void k_gemm1(
    const unsigned short* __restrict__ xb,   // [T][DM] bf16
    const unsigned short* __restrict__ w1t,  // [E][DF][DM] bf16
    const float* __restrict__ b1,            // [E][DF]
    const int* __restrict__ counts, const int* __restrict__ offsets,
    const int* __restrict__ btok, const int* __restrict__ work,
    unsigned short* __restrict__ H,          // [2T][DF] bf16
    const float* __restrict__ W2, unsigned short* __restrict__ w2t,
    int gx) {
  __shared__ __align__(16) union {
    struct { unsigned short A[128 * 64]; unsigned short B[128 * 64]; int tok[128]; } g;
    float tile[64][65];
  } sm;

  int nwg = gx * NSLOT;
  int bid = blockIdx.x;

  if (bid >= nwg) {
    int b2i = bid - nwg;
    int e = b2i >> 10, rem = b2i & 1023;
    int byy = rem >> 4, bxx = rem & 15;
    int r0 = byy * 64, c0 = bxx * 64;
    const float* src = W2 + (size_t)e * DF * DM;
    unsigned short* dst = w2t + (size_t)e * DF * DM;
    int tx = threadIdx.x & 15, ty = threadIdx.x >> 4;
#pragma unroll
    for (int i = 0; i < 4; ++i) {
      int r = ty + i * 16;
      float4 v = *(const float4*)(src + (size_t)(r0 + r) * DM + c0 + tx * 4);
      sm.tile[r][tx * 4 + 0] = v.x; sm.tile[r][tx * 4 + 1] = v.y;
      sm.tile[r][tx * 4 + 2] = v.z; sm.tile[r][tx * 4 + 3] = v.w;
    }
    __syncthreads();
    int tx2 = threadIdx.x & 7, ty2 = threadIdx.x >> 3;
#pragma unroll
    for (int i = 0; i < 2; ++i) {
      int c = ty2 + i * 32;
      ushort8 o;
#pragma unroll
      for (int j = 0; j < 8; ++j) o[j] = f2bf(sm.tile[tx2 * 8 + j][c]);
      *(ushort8*)(dst + (size_t)(c0 + c) * DF + r0 + tx2 * 8) = o;
    }
    return;
  }

  int wg = (bid & 7) * (nwg >> 3) + (bid >> 3);
  int slot = wg / gx;
  int bx = wg - slot * gx;
  int pk = work[slot];
  if (pk < 0) return;
  int e = pk >> 20;
  int m0 = pk & 0xFFFFF;
  int cnt = counts[e];
  int eoff = offsets[e];
  int f0 = bx * 128;
  int tid = threadIdx.x;
  int wave = tid >> 6, lane = tid & 63;

  for (int i = tid; i < 128; i += 256) {
    int p = m0 + i; if (p >= cnt) p = cnt - 1;
    sm.g.tok[i] = btok[e * T_TOK + p];
  }
  __syncthreads();

  int slin = lane & 7, rsub = lane >> 3;
  int ksl8 = (slin ^ rsub) * 8;

  const unsigned short* srcA[4];
  const unsigned short* srcB[4];
  int ldsg[4];
#pragma unroll
  for (int j = 0; j < 4; ++j) {
    int g = j * 4 + wave;
    int m = g * 8 + rsub;
    srcA[j] = xb + (size_t)sm.g.tok[m] * DM + ksl8;
    srcB[j] = w1t + ((size_t)e * DF + f0 + m) * DM + ksl8;
    ldsg[j] = g * 512;
  }

  auto stage = [&](int ks) {
#pragma unroll
    for (int j = 0; j < 4; ++j) {
      __builtin_amdgcn_global_load_lds((const AS1 void*)(srcA[j] + (size_t)ks * 64),
                                       (AS3 void*)(&sm.g.A[ldsg[j]]), 16, 0, 0);
      __builtin_amdgcn_global_load_lds((const AS1 void*)(srcB[j] + (size_t)ks * 64),
                                       (AS3 void*)(&sm.g.B[ldsg[j]]), 16, 0, 0);
    }
  };

  int wm = wave >> 1, wn = wave & 1;
  int lrow = lane & 15, khi = lane >> 4;
  f32x4 acc[4][4];
#pragma unroll
  for (int m = 0; m < 4; ++m)
#pragma unroll
    for (int n = 0; n < 4; ++n) acc[m][n] = (f32x4){0.f, 0.f, 0.f, 0.f};

  auto compute = [&]() {
#pragma unroll
    for (int kk = 0; kk < 2; ++kk) {
      int kslot = kk * 4 + khi;
      short8 af[4], bfv[4];
#pragma unroll
      for (int m = 0; m < 4; ++m) {
        int row = wm * 64 + m * 16 + lrow;
        int slotx = kslot ^ (row & 7);
        af[m] = *(const short8*)(&sm.g.A[row * 64 + slotx * 8]);
      }
#pragma unroll
      for (int n = 0; n < 4; ++n) {
        int row = wn * 64 + n * 16 + lrow;
        int slotx = kslot ^ (row & 7);
        bfv[n] = *(const short8*)(&sm.g.B[row * 64 + slotx * 8]);
      }
#pragma unroll
      for (int m = 0; m < 4; ++m)
#pragma unroll
        for (int n = 0; n < 4; ++n)
          acc[m][n] = __builtin_amdgcn_mfma_f32_16x16x32_bf16(af[m], bfv[n], acc[m][n], 0, 0, 0);
    }
  };

  const int nk = DM / 64;
  for (int ks = 0; ks < nk; ++ks) {
    stage(ks);
    __syncthreads();
    compute();
    __syncthreads();
  }

#pragma unroll
  for (int m = 0; m < 4; ++m) {
    int rbase = wm * 64 + m * 16 + khi * 4;
#pragma unroll
    for (int j = 0; j < 4; ++j) {
      int pos = m0 + rbase + j;
      if (pos < cnt) {
        size_t hrow = (size_t)(eoff + pos) * DF;
#pragma unroll
        for (int n = 0; n < 4; ++n) {
          int fl = f0 + wn * 64 + n * 16 + lrow;
          float v = acc[m][n][j] + b1[e * DF + fl];
          H[hrow + fl] = f2bf(gelu_tanh(v));
        }
      }
    }
  }
}

// GEMM2: BK=128 (steps 64->32; per-step fixed overhead ~4000cyc amortized).
// 16-chunk XOR swizzle: store chunk q^(row&15), read slot kslot^(row&15).
__global__ __launch_bounds__(256, 2) void k_gemm2(
    const unsigned short* __restrict__ H,    // [2T][DF] bf16
    const unsigned short* __restrict__ w2t,  // [E][DM][DF] bf16
    const int* __restrict__ counts, const int* __restrict__ offsets,
    const int* __restrict__ btok, const float* __restrict__ bw,
    const int* __restrict__ work,
    float* __restrict__ out, int gx) {
  __shared__ __align__(16) unsigned short ldsA[128 * 128];
  __shared__ __align__(16) unsigned short ldsB[128 * 128];
  __shared__ int toksh[128];
  __shared__ float wsh[128];

  int nwg = gx * NSLOT;
  int bid = blockIdx.x;
  int wg = (bid & 7) * (nwg >> 3) + (bid >> 3);
  int slot = wg / gx;
  int bx = wg - slot * gx;
  int pk = work[slot];
  if (pk < 0) return;
  int e = pk >> 20;
  int m0 = pk & 0xFFFFF;
  int cnt = counts[e];
  int eoff = offsets[e];
  int d0 = bx * 128;
  int tid = threadIdx.x;
  int wave = tid >> 6, lane = tid & 63;

  for (int i = tid; i < 128; i += 256) {
    int p = m0 + i; if (p >= cnt) p = cnt - 1;
    toksh[i] = btok[e * T_TOK + p];
    wsh[i] = bw[e * T_TOK + p];
  }
  __syncthreads();

  // staging: 2048 16B-slots per operand; thread handles 8 of each.
  // slot s = j*256+tid: row = s>>4 = j*16 + (tid>>4), chunk q = tid&15.
  // row&15 == tid>>4 for all j -> swizzled chunk offset constant per thread.
  int rowt = tid >> 4, qc = tid & 15;
  int chunkoff = (qc ^ rowt) * 8;
  const unsigned short* srcA[8];
#pragma unroll
  for (int j = 0; j < 8; ++j) {
    int row = j * 16 + rowt;
    int p = m0 + row; if (p >= cnt) p = cnt - 1;
    srcA[j] = H + (size_t)(eoff + p) * DF + chunkoff;
  }
  const unsigned short* srcB0 = w2t + ((size_t)e * DM + d0 + rowt) * DF + chunkoff;

  auto stage = [&](int ks) {
#pragma unroll
    for (int j = 0; j < 8; ++j)
      __builtin_amdgcn_global_load_lds((const AS1 void*)(srcA[j] + (size_t)ks * 128),
                                       (AS3 void*)(&ldsA[(j * 256 + tid) * 8]), 16, 0, 0);
#pragma unroll
    for (int j = 0; j < 8; ++j)
      __builtin_amdgcn_global_load_lds(
          (const AS1 void*)(srcB0 + (size_t)j * 16 * DF + (size_t)ks * 128),
          (AS3 void*)(&ldsB[(j * 256 + tid) * 8]), 16, 0, 0);
  };

  int wm = wave >> 1, wn = wave & 1;
  int lrow = lane & 15, khi = lane >> 4;
  f32x4 acc[4][4];
#pragma unroll
  for (int m = 0; m < 4; ++m)
#pragma unroll
    for (int n = 0; n < 4; ++n) acc[m][n] = (f32x4){0.f, 0.f, 0.f, 0.f};

  auto compute = [&]() {
#pragma unroll
    for (int kk = 0; kk < 4; ++kk) {
      int kslot = kk * 4 + khi;
      short8 af[4], bfv[4];
#pragma unroll
      for (int m = 0; m < 4; ++m) {
        int row = wm * 64 + m * 16 + lrow;
        int slotx = kslot ^ (row & 15);
        af[m] = *(const short8*)(&ldsA[row * 128 + slotx * 8]);
      }
#pragma unroll
      for (int n = 0; n < 4; ++n) {
        int row = wn * 64 + n * 16 + lrow;
        int slotx = kslot ^ (row & 15);
        bfv[n] = *(const short8*)(&ldsB[row * 128 + slotx * 8]);
      }
#pragma unroll
      for (int m = 0; m < 4; ++m)
#pragma unroll
        for (int n = 0; n < 4; ++n)
          acc[m][n] = __builtin_amdgcn_mfma_f32_16x16x32_bf16(af[m], bfv[n], acc[m][n], 0, 0, 0);
    }
  };

  const int nk = DF / 128;  // 32
  for (int ks = 0; ks < nk; ++ks) {
    stage(ks);
    __syncthreads();
    compute();
    __syncthreads();
  }

#pragma unroll
  for (int m = 0; m < 4; ++m) {
    int rbase = wm * 64 + m * 16 + khi * 4;
#pragma unroll
    for (int j = 0; j < 4; ++j) {
      int lr = rbase + j;
      int pos = m0 + lr;
      if (pos < cnt) {
        int tok = toksh[lr];
        float wgt = wsh[lr];
#pragma unroll
        for (int n = 0; n < 4; ++n) {
          int dc = d0 + wn * 64 + n * 16 + lrow;
          atomicAdd(&out[(size_t)tok * DM + dc], wgt * acc[m][n][j]);
        }
      }
    }
  }
}

extern "C" void kernel_launch(void* const* d_in, const int* in_sizes, int n_in,
                              void* d_out, int out_size, void* d_ws, size_t ws_size,
                              hipStream_t stream) {
  const float* x  = (const float*)d_in[0];
  const float* Wg = (const float*)d_in[1];
  const float* bg = (const float*)d_in[2];
  const float* W1 = (const float*)d_in[3];
  const float* b1 = (const float*)d_in[4];
  const float* W2 = (const float*)d_in[5];
  const float* b2 = (const float*)d_in[6];
  float* out = (float*)d_out;

  uint8_t* ws = (uint8_t*)d_ws;
  size_t off = 0;
  auto alloc = [&](size_t bytes) {
    size_t o = off;
    off = (off + bytes + 255) & ~(size_t)255;
    return o;
  };
  size_t o_counts = alloc(NE * 4);
  size_t o_offsets = alloc(NE * 4);
  size_t o_work = alloc(NSLOT * 4);
  size_t o_choice = alloc((size_t)2 * T_TOK * 4);
  size_t o_wts = alloc((size_t)2 * T_TOK * 4);
  size_t o_btok = alloc((size_t)NE * T_TOK * 4);
  size_t o_bw = alloc((size_t)NE * T_TOK * 4);
  size_t o_xb = alloc((size_t)T_TOK * DM * 2);
  size_t o_w1t = alloc((size_t)NE * DF * DM * 2);
  size_t o_w2t = alloc((size_t)NE * DM * DF * 2);
  size_t o_h = alloc((size_t)2 * T_TOK * DF * 2);

  if (off > ws_size) {
    k_probe<<<dim3(1024), dim3(256), 0, stream>>>(out, (float)(double)ws_size, out_size);
    return;
  }

  int* counts = (int*)(ws + o_counts);
  int* offsets = (int*)(ws + o_offsets);
  int* work = (int*)(ws + o_work);
  int* choice2 = (int*)(ws + o_choice);
  float* wtsp = (float*)(ws + o_wts);
  int* btok = (int*)(ws + o_btok);
  float* bwp = (float*)(ws + o_bw);
  unsigned short* xb = (unsigned short*)(ws + o_xb);
  unsigned short* w1t = (unsigned short*)(ws + o_w1t);
  unsigned short* w2t = (unsigned short*)(ws + o_w2t);
  unsigned short* Hbuf = (unsigned short*)(ws + o_h);

  k_prep<<<dim3(NB_GATE + NB_T1), dim3(256), 0, stream>>>(
      x, xb, Wg, bg, W1, w1t, b2, out, choice2, wtsp);
  k_bucket<<<dim3(NE), dim3(256), 0, stream>>>(choice2, wtsp, counts, offsets, btok, bwp, work);

  int g1x = DF / 128;  // 32
  int g2x = DM / 128;  // 8
  k_gemm1<<<dim3(g1x * NSLOT + NB_T2), dim3(256), 0, stream>>>(
      xb, w1t, b1, counts, offsets, btok, work, Hbuf, W2, w2t, g1x);
  k_gemm2<<<dim3(g2x * NSLOT), dim3(256), 0, stream>>>(
      Hbuf, w2t, counts, offsets, btok, bwp, work, out, g2x);
}

// Round 22
// 531.880 us; speedup vs baseline: 1.0225x; 1.0225x over previous
//
#include <hip/hip_runtime.h>
#include <hip/hip_bf16.h>
#include <stdint.h>

#define T_TOK 8192
#define DM 1024
#define DF 4096
#define NE 8
#define NSLOT 136   // max live by-slots: 16384/128 + 8

typedef __attribute__((ext_vector_type(8))) short short8;
typedef __attribute__((ext_vector_type(8))) unsigned short ushort8;
typedef __attribute__((ext_vector_type(4))) float f32x4;

#define AS1 __attribute__((address_space(1)))
#define AS3 __attribute__((address_space(3)))

#define NB_GATE (T_TOK / 4)                    // 2048
#define NB_T1 ((DF / 64) * (DM / 64) * NE)     // 8192
#define NB_T2 ((DM / 64) * (DF / 64) * NE)     // 8192

static __device__ __forceinline__ unsigned short f2bf(float f) {
  union { float f; unsigned int u; } c; c.f = f;
  unsigned int u = c.u;
  unsigned int r = (u + 0x7FFFu + ((u >> 16) & 1u)) >> 16;
  return (unsigned short)r;
}

static __device__ __forceinline__ float gelu_tanh(float v) {
  float y = 0.7978845608028654f * (v + 0.044715f * v * v * v);
  float ay = fabsf(y);
  float e = __expf(-2.0f * ay);
  float th = (1.0f - e) / (1.0f + e);
  th = copysignf(th, y);
  return 0.5f * v * (1.0f + th);
}

__global__ void k_probe(float* out, float v, int n) {
  int i = blockIdx.x * blockDim.x + threadIdx.x;
  for (; i < n; i += gridDim.x * blockDim.x) out[i] = v;
}

// Fused prologue: [0,NB_GATE) gate+out-init; then W1 transpose ONLY.
// (W2 transpose is folded into k_gemm1's grid — gemm2 is its first consumer.)
__global__ void k_prep(const float* __restrict__ x, unsigned short* __restrict__ xb,
                       const float* __restrict__ Wg, const float* __restrict__ bg,
                       const float* __restrict__ W1, unsigned short* __restrict__ w1t,
                       const float* __restrict__ b2, float* __restrict__ out,
                       int* __restrict__ choice2, float* __restrict__ wts) {
  __shared__ float tile[64][65];
  int bid = blockIdx.x;

  if (bid < NB_GATE) {
    int wave = threadIdx.x >> 6, lane = threadIdx.x & 63;
    int t = bid * 4 + wave;
    const float* xr = x + (size_t)t * DM;
    unsigned short* xo = xb + (size_t)t * DM;
    double acc[NE];
#pragma unroll
    for (int e = 0; e < NE; ++e) acc[e] = 0.0;
#pragma unroll
    for (int i = 0; i < 4; ++i) {
      int d = lane * 4 + i * 256;
      float4 v = *(const float4*)(xr + d);
      ushort4 o;
      o.x = f2bf(v.x); o.y = f2bf(v.y); o.z = f2bf(v.z); o.w = f2bf(v.w);
      *(ushort4*)(xo + d) = o;
      float xv[4] = {v.x, v.y, v.z, v.w};
#pragma unroll
      for (int q = 0; q < 4; ++q) {
        const float4* wg = (const float4*)(Wg + (size_t)(d + q) * NE);
        float4 w0 = wg[0], w1 = wg[1];
        acc[0] += (double)xv[q] * w0.x; acc[1] += (double)xv[q] * w0.y;
        acc[2] += (double)xv[q] * w0.z; acc[3] += (double)xv[q] * w0.w;
        acc[4] += (double)xv[q] * w1.x; acc[5] += (double)xv[q] * w1.y;
        acc[6] += (double)xv[q] * w1.z; acc[7] += (double)xv[q] * w1.w;
      }
    }
#pragma unroll
    for (int off = 32; off; off >>= 1)
#pragma unroll
      for (int e = 0; e < NE; ++e) acc[e] += __shfl_xor(acc[e], off);
    int e1i = 0, e2i = 0;
    float w1v = 0.f, w2v = 0.f;
    if (lane == 0) {
      float lg[NE];
#pragma unroll
      for (int e = 0; e < NE; ++e) lg[e] = (float)acc[e] + bg[e];
      float m = lg[0];
#pragma unroll
      for (int e = 1; e < NE; ++e) m = fmaxf(m, lg[e]);
      float s = 0.f, p[NE];
#pragma unroll
      for (int e = 0; e < NE; ++e) { p[e] = expf(lg[e] - m); s += p[e]; }
      float inv = 1.f / s;
      int i1 = 0;
#pragma unroll
      for (int e = 1; e < NE; ++e) if (lg[e] > lg[i1]) i1 = e;
      int i2 = (i1 == 0) ? 1 : 0;
#pragma unroll
      for (int e = 0; e < NE; ++e) if (e != i1 && lg[e] > lg[i2]) i2 = e;
      e1i = i1; e2i = i2;
      w1v = p[i1] * inv; w2v = p[i2] * inv;
      choice2[2 * t] = i1;     wts[2 * t] = w1v;
      choice2[2 * t + 1] = i2; wts[2 * t + 1] = w2v;
    }
    e1i = __shfl(e1i, 0); e2i = __shfl(e2i, 0);
    w1v = __shfl(w1v, 0); w2v = __shfl(w2v, 0);
#pragma unroll
    for (int i = 0; i < 4; ++i) {
      int d = lane * 4 + i * 256;
      float4 a = *(const float4*)(b2 + (size_t)e1i * DM + d);
      float4 b = *(const float4*)(b2 + (size_t)e2i * DM + d);
      float4 o;
      o.x = w1v * a.x + w2v * b.x; o.y = w1v * a.y + w2v * b.y;
      o.z = w1v * a.z + w2v * b.z; o.w = w1v * a.w + w2v * b.w;
      *(float4*)(out + (size_t)t * DM + d) = o;
    }
    return;
  }

  // W1 transpose: [E][DM][DF] fp32 -> [E][DF][DM] bf16
  {
    int b2i = bid - NB_GATE;
    int e = b2i >> 10, rem = b2i & 1023;
    int byy = rem >> 6, bxx = rem & 63;
    int r0 = byy * 64, c0 = bxx * 64;
    const float* src = W1 + (size_t)e * DM * DF;
    unsigned short* dst = w1t + (size_t)e * DM * DF;
    int tx = threadIdx.x & 15, ty = threadIdx.x >> 4;
#pragma unroll
    for (int i = 0; i < 4; ++i) {
      int r = ty + i * 16;
      float4 v = *(const float4*)(src + (size_t)(r0 + r) * DF + c0 + tx * 4);
      tile[r][tx * 4 + 0] = v.x; tile[r][tx * 4 + 1] = v.y;
      tile[r][tx * 4 + 2] = v.z; tile[r][tx * 4 + 3] = v.w;
    }
    __syncthreads();
    int tx2 = threadIdx.x & 7, ty2 = threadIdx.x >> 3;
#pragma unroll
    for (int i = 0; i < 2; ++i) {
      int c = ty2 + i * 32;
      ushort8 o;
#pragma unroll
      for (int j = 0; j < 8; ++j) o[j] = f2bf(tile[tx2 * 8 + j][c]);
      *(ushort8*)(dst + (size_t)(c0 + c) * DM + r0 + tx2 * 8) = o;
    }
  }
}

// Parallel deterministic compaction: 8 blocks (one per expert) x 4 waves.
__global__ void k_bucket(const int* __restrict__ choice2, const float* __restrict__ wts,
                         int* __restrict__ counts, int* __restrict__ offsets,
                         int* __restrict__ btok, float* __restrict__ bw,
                         int* __restrict__ work) {
  __shared__ int qc[4][NE];
  int e = blockIdx.x;
  int tid = threadIdx.x;
  int w = tid >> 6, lane = tid & 63;
  const int QUARTER = 2 * T_TOK / 4;  // 4096
  int base = w * QUARTER;
  unsigned long long below = (lane == 0) ? 0ull : ((1ull << lane) - 1ull);

  int cq[NE];
#pragma unroll
  for (int q = 0; q < NE; ++q) cq[q] = 0;
  for (int i0 = 0; i0 < QUARTER; i0 += 64) {
    int ce = choice2[base + i0 + lane];
#pragma unroll
    for (int q = 0; q < NE; ++q)
      cq[q] += (int)__popcll(__ballot(ce == q));
  }
  if (lane == 0) {
#pragma unroll
    for (int q = 0; q < NE; ++q) qc[w][q] = cq[q];
  }
  __syncthreads();

  int total[NE];
#pragma unroll
  for (int q = 0; q < NE; ++q) total[q] = qc[0][q] + qc[1][q] + qc[2][q] + qc[3][q];
  int pos = 0;
#pragma unroll
  for (int ww = 0; ww < 4; ++ww) if (ww < w) pos += qc[ww][e];

  if (e == 0 && tid == 0) {
    int s = 0;
    for (int q = 0; q < NE; ++q) { counts[q] = total[q]; offsets[q] = s; s += total[q]; }
    int idx = 0;
    for (int q = 0; q < NE; ++q) {
      int nby = (total[q] + 127) >> 7;
      for (int j = 0; j < nby; ++j) work[idx++] = (q << 20) | (j << 7);
    }
    while (idx < NSLOT) work[idx++] = -1;
  }

  for (int i0 = 0; i0 < QUARTER; i0 += 64) {
    int idx = base + i0 + lane;
    int ce = choice2[idx];
    float wt = wts[idx];
    unsigned long long m = __ballot(ce == e);
    if (ce == e) {
      int r = (int)__popcll(m & below);
      btok[e * T_TOK + pos + r] = idx >> 1;
      bw[e * T_TOK + pos + r] = wt;
    }
    pos += (int)__popcll(m);
  }
}

// GEMM1 (BK=64, R17 core) + W2-transpose carrier (R20 win).
__global__ __launch_bounds__(256, 4) void k_gemm1(
    const unsigned short* __restrict__ xb,   // [T][DM] bf16
    const unsigned short* __restrict__ w1t,  // [E][DF][DM] bf16
    const float* __restrict__ b1,            // [E][DF]
    const int* __restrict__ counts, const int* __restrict__ offsets,
    const int* __restrict__ btok, const int* __restrict__ work,
    unsigned short* __restrict__ H,          // [2T][DF] bf16
    const float* __restrict__ W2, unsigned short* __restrict__ w2t,
    int gx) {
  __shared__ __align__(16) union {
    struct { unsigned short A[128 * 64]; unsigned short B[128 * 64]; int tok[128]; } g;
    float tile[64][65];
  } sm;

  int nwg = gx * NSLOT;
  int bid = blockIdx.x;

  if (bid >= nwg) {
    int b2i = bid - nwg;
    int e = b2i >> 10, rem = b2i & 1023;
    int byy = rem >> 4, bxx = rem & 15;
    int r0 = byy * 64, c0 = bxx * 64;
    const float* src = W2 + (size_t)e * DF * DM;
    unsigned short* dst = w2t + (size_t)e * DF * DM;
    int tx = threadIdx.x & 15, ty = threadIdx.x >> 4;
#pragma unroll
    for (int i = 0; i < 4; ++i) {
      int r = ty + i * 16;
      float4 v = *(const float4*)(src + (size_t)(r0 + r) * DM + c0 + tx * 4);
      sm.tile[r][tx * 4 + 0] = v.x; sm.tile[r][tx * 4 + 1] = v.y;
      sm.tile[r][tx * 4 + 2] = v.z; sm.tile[r][tx * 4 + 3] = v.w;
    }
    __syncthreads();
    int tx2 = threadIdx.x & 7, ty2 = threadIdx.x >> 3;
#pragma unroll
    for (int i = 0; i < 2; ++i) {
      int c = ty2 + i * 32;
      ushort8 o;
#pragma unroll
      for (int j = 0; j < 8; ++j) o[j] = f2bf(sm.tile[tx2 * 8 + j][c]);
      *(ushort8*)(dst + (size_t)(c0 + c) * DF + r0 + tx2 * 8) = o;
    }
    return;
  }

  int wg = (bid & 7) * (nwg >> 3) + (bid >> 3);
  int slot = wg / gx;
  int bx = wg - slot * gx;
  int pk = work[slot];
  if (pk < 0) return;
  int e = pk >> 20;
  int m0 = pk & 0xFFFFF;
  int cnt = counts[e];
  int eoff = offsets[e];
  int f0 = bx * 128;
  int tid = threadIdx.x;
  int wave = tid >> 6, lane = tid & 63;

  for (int i = tid; i < 128; i += 256) {
    int p = m0 + i; if (p >= cnt) p = cnt - 1;
    sm.g.tok[i] = btok[e * T_TOK + p];
  }
  __syncthreads();

  int slin = lane & 7, rsub = lane >> 3;
  int ksl8 = (slin ^ rsub) * 8;

  const unsigned short* srcA[4];
  const unsigned short* srcB[4];
  int ldsg[4];
#pragma unroll
  for (int j = 0; j < 4; ++j) {
    int g = j * 4 + wave;
    int m = g * 8 + rsub;
    srcA[j] = xb + (size_t)sm.g.tok[m] * DM + ksl8;
    srcB[j] = w1t + ((size_t)e * DF + f0 + m) * DM + ksl8;
    ldsg[j] = g * 512;
  }

  auto stage = [&](int ks) {
#pragma unroll
    for (int j = 0; j < 4; ++j) {
      __builtin_amdgcn_global_load_lds((const AS1 void*)(srcA[j] + (size_t)ks * 64),
                                       (AS3 void*)(&sm.g.A[ldsg[j]]), 16, 0, 0);
      __builtin_amdgcn_global_load_lds((const AS1 void*)(srcB[j] + (size_t)ks * 64),
                                       (AS3 void*)(&sm.g.B[ldsg[j]]), 16, 0, 0);
    }
  };

  int wm = wave >> 1, wn = wave & 1;
  int lrow = lane & 15, khi = lane >> 4;
  f32x4 acc[4][4];
#pragma unroll
  for (int m = 0; m < 4; ++m)
#pragma unroll
    for (int n = 0; n < 4; ++n) acc[m][n] = (f32x4){0.f, 0.f, 0.f, 0.f};

  auto compute = [&]() {
#pragma unroll
    for (int kk = 0; kk < 2; ++kk) {
      int kslot = kk * 4 + khi;
      short8 af[4], bfv[4];
#pragma unroll
      for (int m = 0; m < 4; ++m) {
        int row = wm * 64 + m * 16 + lrow;
        int slotx = kslot ^ (row & 7);
        af[m] = *(const short8*)(&sm.g.A[row * 64 + slotx * 8]);
      }
#pragma unroll
      for (int n = 0; n < 4; ++n) {
        int row = wn * 64 + n * 16 + lrow;
        int slotx = kslot ^ (row & 7);
        bfv[n] = *(const short8*)(&sm.g.B[row * 64 + slotx * 8]);
      }
#pragma unroll
      for (int m = 0; m < 4; ++m)
#pragma unroll
        for (int n = 0; n < 4; ++n)
          acc[m][n] = __builtin_amdgcn_mfma_f32_16x16x32_bf16(af[m], bfv[n], acc[m][n], 0, 0, 0);
    }
  };

  const int nk = DM / 64;
  for (int ks = 0; ks < nk; ++ks) {
    stage(ks);
    __syncthreads();
    compute();
    __syncthreads();
  }

#pragma unroll
  for (int m = 0; m < 4; ++m) {
    int rbase = wm * 64 + m * 16 + khi * 4;
#pragma unroll
    for (int j = 0; j < 4; ++j) {
      int pos = m0 + rbase + j;
      if (pos < cnt) {
        size_t hrow = (size_t)(eoff + pos) * DF;
#pragma unroll
        for (int n = 0; n < 4; ++n) {
          int fl = f0 + wn * 64 + n * 16 + lrow;
          float v = acc[m][n][j] + b1[e * DF + fl];
          H[hrow + fl] = f2bf(gelu_tanh(v));
        }
      }
    }
  }
}

// GEMM2: out[tok][d] += w * (H[slot] @ W2)   (bias pre-applied by k_prep)
__global__ __launch_bounds__(256, 4) void k_gemm2(
    const unsigned short* __restrict__ H,    // [2T][DF] bf16
    const unsigned short* __restrict__ w2t,  // [E][DM][DF] bf16
    const int* __restrict__ counts, const int* __restrict__ offsets,
    const int* __restrict__ btok, const float* __restrict__ bw,
    const int* __restrict__ work,
    float* __restrict__ out, int gx) {
  __shared__ __align__(16) unsigned short ldsA[128 * 64];
  __shared__ __align__(16) unsigned short ldsB[128 * 64];
  __shared__ int toksh[128];
  __shared__ float wsh[128];

  int nwg = gx * NSLOT;
  int bid = blockIdx.x;
  int wg = (bid & 7) * (nwg >> 3) + (bid >> 3);
  int slot = wg / gx;
  int bx = wg - slot * gx;
  int pk = work[slot];
  if (pk < 0) return;
  int e = pk >> 20;
  int m0 = pk & 0xFFFFF;
  int cnt = counts[e];
  int eoff = offsets[e];
  int d0 = bx * 128;
  int tid = threadIdx.x;
  int wave = tid >> 6, lane = tid & 63;

  for (int i = tid; i < 128; i += 256) {
    int p = m0 + i; if (p >= cnt) p = cnt - 1;
    toksh[i] = btok[e * T_TOK + p];
    wsh[i] = bw[e * T_TOK + p];
  }
  __syncthreads();

  int slin = lane & 7, rsub = lane >> 3;
  int ksl8 = (slin ^ rsub) * 8;

  const unsigned short* srcA[4];
  const unsigned short* srcB[4];
  int ldsg[4];
#pragma unroll
  for (int j = 0; j < 4; ++j) {
    int g = j * 4 + wave;
    int m = g * 8 + rsub;
    int p = m0 + m; if (p >= cnt) p = cnt - 1;
    srcA[j] = H + (size_t)(eoff + p) * DF + ksl8;
    srcB[j] = w2t + ((size_t)e * DM + d0 + m) * DF + ksl8;
    ldsg[j] = g * 512;
  }

  auto stage = [&](int ks) {
#pragma unroll
    for (int j = 0; j < 4; ++j) {
      __builtin_amdgcn_global_load_lds((const AS1 void*)(srcA[j] + (size_t)ks * 64),
                                       (AS3 void*)(&ldsA[ldsg[j]]), 16, 0, 0);
      __builtin_amdgcn_global_load_lds((const AS1 void*)(srcB[j] + (size_t)ks * 64),
                                       (AS3 void*)(&ldsB[ldsg[j]]), 16, 0, 0);
    }
  };

  int wm = wave >> 1, wn = wave & 1;
  int lrow = lane & 15, khi = lane >> 4;
  f32x4 acc[4][4];
#pragma unroll
  for (int m = 0; m < 4; ++m)
#pragma unroll
    for (int n = 0; n < 4; ++n) acc[m][n] = (f32x4){0.f, 0.f, 0.f, 0.f};

  auto compute = [&]() {
#pragma unroll
    for (int kk = 0; kk < 2; ++kk) {
      int kslot = kk * 4 + khi;
      short8 af[4], bfv[4];
#pragma unroll
      for (int m = 0; m < 4; ++m) {
        int row = wm * 64 + m * 16 + lrow;
        int slotx = kslot ^ (row & 7);
        af[m] = *(const short8*)(&ldsA[row * 64 + slotx * 8]);
      }
#pragma unroll
      for (int n = 0; n < 4; ++n) {
        int row = wn * 64 + n * 16 + lrow;
        int slotx = kslot ^ (row & 7);
        bfv[n] = *(const short8*)(&ldsB[row * 64 + slotx * 8]);
      }
#pragma unroll
      for (int m = 0; m < 4; ++m)
#pragma unroll
        for (int n = 0; n < 4; ++n)
          acc[m][n] = __builtin_amdgcn_mfma_f32_16x16x32_bf16(af[m], bfv[n], acc[m][n], 0, 0, 0);
    }
  };

  const int nk = DF / 64;
  for (int ks = 0; ks < nk; ++ks) {
    stage(ks);
    __syncthreads();
    compute();
    __syncthreads();
  }

#pragma unroll
  for (int m = 0; m < 4; ++m) {
    int rbase = wm * 64 + m * 16 + khi * 4;
#pragma unroll
    for (int j = 0; j < 4; ++j) {
      int lr = rbase + j;
      int pos = m0 + lr;
      if (pos < cnt) {
        int tok = toksh[lr];
        float wgt = wsh[lr];
#pragma unroll
        for (int n = 0; n < 4; ++n) {
          int dc = d0 + wn * 64 + n * 16 + lrow;
          atomicAdd(&out[(size_t)tok * DM + dc], wgt * acc[m][n][j]);
        }
      }
    }
  }
}

extern "C" void kernel_launch(void* const* d_in, const int* in_sizes, int n_in,
                              void* d_out, int out_size, void* d_ws, size_t ws_size,
                              hipStream_t stream) {
  const float* x  = (const float*)d_in[0];
  const float* Wg = (const float*)d_in[1];
  const float* bg = (const float*)d_in[2];
  const float* W1 = (const float*)d_in[3];
  const float* b1 = (const float*)d_in[4];
  const float* W2 = (const float*)d_in[5];
  const float* b2 = (const float*)d_in[6];
  float* out = (float*)d_out;

  uint8_t* ws = (uint8_t*)d_ws;
  size_t off = 0;
  auto alloc = [&](size_t bytes) {
    size_t o = off;
    off = (off + bytes + 255) & ~(size_t)255;
    return o;
  };
  size_t o_counts = alloc(NE * 4);
  size_t o_offsets = alloc(NE * 4);
  size_t o_work = alloc(NSLOT * 4);
  size_t o_choice = alloc((size_t)2 * T_TOK * 4);
  size_t o_wts = alloc((size_t)2 * T_TOK * 4);
  size_t o_btok = alloc((size_t)NE * T_TOK * 4);
  size_t o_bw = alloc((size_t)NE * T_TOK * 4);
  size_t o_xb = alloc((size_t)T_TOK * DM * 2);
  size_t o_w1t = alloc((size_t)NE * DF * DM * 2);
  size_t o_w2t = alloc((size_t)NE * DM * DF * 2);
  size_t o_h = alloc((size_t)2 * T_TOK * DF * 2);

  if (off > ws_size) {
    k_probe<<<dim3(1024), dim3(256), 0, stream>>>(out, (float)(double)ws_size, out_size);
    return;
  }

  int* counts = (int*)(ws + o_counts);
  int* offsets = (int*)(ws + o_offsets);
  int* work = (int*)(ws + o_work);
  int* choice2 = (int*)(ws + o_choice);
  float* wtsp = (float*)(ws + o_wts);
  int* btok = (int*)(ws + o_btok);
  float* bwp = (float*)(ws + o_bw);
  unsigned short* xb = (unsigned short*)(ws + o_xb);
  unsigned short* w1t = (unsigned short*)(ws + o_w1t);
  unsigned short* w2t = (unsigned short*)(ws + o_w2t);
  unsigned short* Hbuf = (unsigned short*)(ws + o_h);

  k_prep<<<dim3(NB_GATE + NB_T1), dim3(256), 0, stream>>>(
      x, xb, Wg, bg, W1, w1t, b2, out, choice2, wtsp);
  k_bucket<<<dim3(NE), dim3(256), 0, stream>>>(choice2, wtsp, counts, offsets, btok, bwp, work);

  int g1x = DF / 128;  // 32
  int g2x = DM / 128;  // 8
  k_gemm1<<<dim3(g1x * NSLOT + NB_T2), dim3(256), 0, stream>>>(
      xb, w1t, b1, counts, offsets, btok, work, Hbuf, W2, w2t, g1x);
  k_gemm2<<<dim3(g2x * NSLOT), dim3(256), 0, stream>>>(
      Hbuf, w2t, counts, offsets, btok, bwp, work, out, g2x);
}